// Round 10
// baseline (133.634 us; speedup 1.0000x reference)
//
#include <hip/hip_runtime.h>
#include <hip/hip_bf16.h>
#include <math.h>

#define NQ 13294
#define NV 13294
#define M_ROWS (2*NQ)     // 26588
#define MP 26624          // padded row count (416*64)

typedef __attribute__((ext_vector_type(8))) short bf16x8;
typedef __attribute__((ext_vector_type(4))) float f32x4;

__device__ __forceinline__ float4 ld4(const float* p){ return *(const float4*)p; }
__device__ __forceinline__ float bfu_lo(unsigned int u){ return __uint_as_float(u << 16); }
__device__ __forceinline__ float bfu_hi(unsigned int u){ return __uint_as_float(u & 0xffff0000u); }
__device__ __forceinline__ unsigned short f2bf(float f){
  unsigned int u = __float_as_uint(f);
  u += 0x7fffu + ((u >> 16) & 1u);   // RNE
  return (unsigned short)(u >> 16);
}
__device__ __forceinline__ unsigned int pk2(float a, float b){
  return (unsigned int)f2bf(a) | ((unsigned int)f2bf(b) << 16);
}
__device__ __forceinline__ void gl_lds16(const unsigned short* g, unsigned short* l) {
  __builtin_amdgcn_global_load_lds(
      (const __attribute__((address_space(1))) unsigned int*)g,
      (__attribute__((address_space(3))) unsigned int*)l, 16, 0, 0);
}

// ---- prep: transpose 5 weights f32 [K][N] -> bf16 [N][K] (K=256) ----
__global__ __launch_bounds__(256) void prep_w(
    const float* __restrict__ wv, const float* __restrict__ wo,
    const float* __restrict__ wa, const float* __restrict__ wu,
    const float* __restrict__ wf, unsigned short* __restrict__ wt)
{
  int t = blockIdx.x * 256 + threadIdx.x;
  if (t >= 294912) return;
  const float* src; int Nn; int base;
  if      (t < 65536)  { src = wv; Nn = 256; base = 0; }
  else if (t < 131072) { src = wo; Nn = 256; base = 65536; }
  else if (t < 163840) { src = wa; Nn = 128; base = 131072; }
  else if (t < 229376) { src = wu; Nn = 256; base = 163840; }
  else                 { src = wf; Nn = 256; base = 229376; }
  const int local = t - base;
  const int n = local >> 8, k = local & 255;
  wt[t] = f2bf(src[k * Nn + n]);
}

// ---- merged v-GEMM + oa-GEMM, one dispatch ----
// Blocks [0,1664): v = value @ Wv^T + b_value -> vbuf2 head-split bf16 (NCOL=4)
// Blocks [1664,4160): [off|attn] = (query+qpos) @ Woa^T + biases -> oa bf16 (NCOL=6)
// A is f32, converted inline during reg-staged LDS fill; B via global_load_lds.
__global__ __launch_bounds__(256) void gemm_voa(
    const float* __restrict__ value, const float* __restrict__ query,
    const float* __restrict__ qpos,
    const unsigned short* __restrict__ wv_t, const unsigned short* __restrict__ woa_t,
    const float* __restrict__ b_value, const float* __restrict__ b_off,
    const float* __restrict__ b_attn,
    unsigned short* __restrict__ vbuf2, unsigned short* __restrict__ oa)
{
  __shared__ unsigned short lds[32768];   // As [0,16384) | Bs [16384,32768)

  const bool is_v = blockIdx.x < 1664;
  const int  ncol = is_v ? 4 : 6;
  const int  lin  = is_v ? blockIdx.x : blockIdx.x - 1664;
  const int  nwg  = is_v ? 1664 : 2496;
  const int  N    = is_v ? 256 : 384;
  const unsigned short* Bt = is_v ? wv_t : woa_t;

  const int swz  = (lin & 7) * (nwg >> 3) + (lin >> 3);
  const int brow = (swz / ncol) * 64;
  const int bcol = (swz % ncol) * 64;

  const int tid  = threadIdx.x;
  const int wid  = tid >> 6, lane = tid & 63;
  const int wr   = wid >> 1, wc = wid & 1;
  const int fr   = lane & 15, fg = lane >> 4;

  // ---- stage B (bf16 weights) via global_load_lds, pre-swizzled source ----
  {
    const int r0   = lane >> 3;      // 0..7
    const int slot = lane & 7;       // 16B slot
    #pragma unroll
    for (int t = 0; t < 4; ++t) {
      #pragma unroll
      for (int c = 0; c < 2; ++c) {
        const int row = (wid * 2 + c) * 8 + r0;
        const int gsl = slot ^ (row & 7);
        gl_lds16(Bt + (size_t)(bcol + row) * 256 + t * 64 + (gsl << 3),
                 &lds[16384 + t * 4096 + (wid * 2 + c) * 512]);
      }
    }
  }
  // ---- stage A (f32 -> bf16 inline), swizzled ds_write ----
  {
    const int srow = tid >> 3;          // 0..31
    const int slot = tid & 7;           // 16B slot
    const int ke0  = slot << 3;         // element col 0..56
    #pragma unroll
    for (int t = 0; t < 4; ++t) {
      #pragma unroll
      for (int c = 0; c < 2; ++c) {
        const int row = c * 32 + srow;
        const int gr  = brow + row;
        const int ke  = t * 64 + ke0;
        float4 f0 = make_float4(0.f,0.f,0.f,0.f), f1 = f0;
        if (gr < M_ROWS) {
          if (is_v) {
            f0 = ld4(value + (size_t)gr * 256 + ke);
            f1 = ld4(value + (size_t)gr * 256 + ke + 4);
          } else {
            f0 = ld4(query + (size_t)gr * 256 + ke);
            f1 = ld4(query + (size_t)gr * 256 + ke + 4);
            float4 g0 = ld4(qpos + (size_t)gr * 256 + ke);
            float4 g1 = ld4(qpos + (size_t)gr * 256 + ke + 4);
            f0.x += g0.x; f0.y += g0.y; f0.z += g0.z; f0.w += g0.w;
            f1.x += g1.x; f1.y += g1.y; f1.z += g1.z; f1.w += g1.w;
          }
        }
        uint4 pk;
        pk.x = pk2(f0.x, f0.y); pk.y = pk2(f0.z, f0.w);
        pk.z = pk2(f1.x, f1.y); pk.w = pk2(f1.z, f1.w);
        const int sw = slot ^ (row & 7);
        *(uint4*)((char*)&lds[t * 4096] + row * 128 + (sw << 4)) = pk;
      }
    }
  }
  __syncthreads();   // drains vmcnt (B) + lgkm (A writes)

  f32x4 acc[2][2];
  #pragma unroll
  for (int m = 0; m < 2; ++m)
    #pragma unroll
    for (int n = 0; n < 2; ++n)
      acc[m][n] = (f32x4){0.f, 0.f, 0.f, 0.f};

  #pragma unroll
  for (int t = 0; t < 4; ++t) {
    const char* as = (const char*)&lds[t * 4096];
    const char* bs = (const char*)&lds[16384 + t * 4096];
    #pragma unroll
    for (int kk = 0; kk < 2; ++kk) {
      const int kb = kk * 64 + fg * 16;
      bf16x8 af[2], bfv[2];
      #pragma unroll
      for (int m = 0; m < 2; ++m) {
        const int r = wr * 32 + m * 16 + fr;
        af[m] = *(const bf16x8*)(as + r * 128 + (kb ^ ((r & 7) << 4)));
      }
      #pragma unroll
      for (int n = 0; n < 2; ++n) {
        const int r = wc * 32 + n * 16 + fr;
        bfv[n] = *(const bf16x8*)(bs + r * 128 + (kb ^ ((r & 7) << 4)));
      }
      #pragma unroll
      for (int m = 0; m < 2; ++m)
        #pragma unroll
        for (int n = 0; n < 2; ++n)
          acc[m][n] = __builtin_amdgcn_mfma_f32_16x16x32_bf16(af[m], bfv[n], acc[m][n], 0, 0, 0);
    }
  }

  // ---- epilogue: acc -> LDS f32 -> coalesced bf16 stores ----
  __syncthreads();
  float* csh = (float*)lds;
  const int c0 = bcol + wc * 32 + fr;
  const int c1 = c0 + 16;
  float bn0, bn1;
  if (is_v) { bn0 = b_value[c0]; bn1 = b_value[c1]; }
  else {
    bn0 = (c0 < 256) ? b_off[c0] : b_attn[c0 - 256];
    bn1 = (c1 < 256) ? b_off[c1] : b_attn[c1 - 256];
  }
  #pragma unroll
  for (int m = 0; m < 2; ++m)
    #pragma unroll
    for (int j = 0; j < 4; ++j) {
      const int row = wr * 32 + m * 16 + fg * 4 + j;
      csh[row * 64 + wc * 32 + fr]      = acc[m][0][j] + bn0;
      csh[row * 64 + wc * 32 + 16 + fr] = acc[m][1][j] + bn1;
    }
  __syncthreads();
  #pragma unroll
  for (int i = 0; i < 4; ++i) {
    const int rl = i * 16 + (tid >> 4);
    const int gr = brow + rl;
    if (gr >= M_ROWS) continue;
    const int c4 = (tid & 15) * 4;
    float4 v = *(const float4*)&csh[rl * 64 + c4];
    ushort4 pk = make_ushort4(f2bf(v.x), f2bf(v.y), f2bf(v.z), f2bf(v.w));
    if (is_v) {
      const int head = (bcol + c4) >> 5;
      const int ch   = c4 & 31;
      *(ushort4*)&vbuf2[((size_t)head * M_ROWS + gr) * 32 + ch] = pk;
    } else {
      *(ushort4*)&oa[(size_t)gr * 384 + bcol + c4] = pk;
    }
  }
}

// ---- bf16-A GEMM (out / ffn), full-K LDS via global_load_lds ----
// OUT_MODE: 0 = f32 rows, 1 = bf16 rows; ADD_RES adds f32 RES.
template<int NCOL, int OUT_MODE, bool ADD_RES>
__global__ __launch_bounds__(256) void gemm_gl(
    const unsigned short* __restrict__ A, const unsigned short* __restrict__ Bt,
    const float* __restrict__ bias, const float* __restrict__ RES,
    void* __restrict__ Cv, int N)
{
  __shared__ unsigned short lds[32768];

  const int nwg = 416 * NCOL;
  const int lin = blockIdx.x;
  const int swz = (lin & 7) * (nwg >> 3) + (lin >> 3);
  const int brow = (swz / NCOL) * 64;
  const int bcol = (swz % NCOL) * 64;

  const int tid  = threadIdx.x;
  const int wid  = tid >> 6, lane = tid & 63;
  const int wr   = wid >> 1, wc = wid & 1;
  const int fr   = lane & 15, fg = lane >> 4;

  {
    const int r0   = lane >> 3;
    const int slot = lane & 7;
    #pragma unroll
    for (int t = 0; t < 4; ++t) {
      #pragma unroll
      for (int c = 0; c < 2; ++c) {
        const int row = (wid * 2 + c) * 8 + r0;
        const int gsl = slot ^ (row & 7);
        gl_lds16(A  + (size_t)(brow + row) * 256 + t * 64 + (gsl << 3),
                 &lds[t * 4096 + (wid * 2 + c) * 512]);
        gl_lds16(Bt + (size_t)(bcol + row) * 256 + t * 64 + (gsl << 3),
                 &lds[16384 + t * 4096 + (wid * 2 + c) * 512]);
      }
    }
  }
  __syncthreads();

  f32x4 acc[2][2];
  #pragma unroll
  for (int m = 0; m < 2; ++m)
    #pragma unroll
    for (int n = 0; n < 2; ++n)
      acc[m][n] = (f32x4){0.f, 0.f, 0.f, 0.f};

  #pragma unroll
  for (int t = 0; t < 4; ++t) {
    const char* as = (const char*)&lds[t * 4096];
    const char* bs = (const char*)&lds[16384 + t * 4096];
    #pragma unroll
    for (int kk = 0; kk < 2; ++kk) {
      const int kb = kk * 64 + fg * 16;
      bf16x8 af[2], bfv[2];
      #pragma unroll
      for (int m = 0; m < 2; ++m) {
        const int r = wr * 32 + m * 16 + fr;
        af[m] = *(const bf16x8*)(as + r * 128 + (kb ^ ((r & 7) << 4)));
      }
      #pragma unroll
      for (int n = 0; n < 2; ++n) {
        const int r = wc * 32 + n * 16 + fr;
        bfv[n] = *(const bf16x8*)(bs + r * 128 + (kb ^ ((r & 7) << 4)));
      }
      #pragma unroll
      for (int m = 0; m < 2; ++m)
        #pragma unroll
        for (int n = 0; n < 2; ++n)
          acc[m][n] = __builtin_amdgcn_mfma_f32_16x16x32_bf16(af[m], bfv[n], acc[m][n], 0, 0, 0);
    }
  }

  __syncthreads();
  float* csh = (float*)lds;
  const int c0 = bcol + wc * 32 + fr;
  const int c1 = c0 + 16;
  const float bn0 = bias[c0];
  const float bn1 = bias[c1];
  #pragma unroll
  for (int m = 0; m < 2; ++m)
    #pragma unroll
    for (int j = 0; j < 4; ++j) {
      const int row = wr * 32 + m * 16 + fg * 4 + j;
      csh[row * 64 + wc * 32 + fr]      = acc[m][0][j] + bn0;
      csh[row * 64 + wc * 32 + 16 + fr] = acc[m][1][j] + bn1;
    }
  __syncthreads();
  #pragma unroll
  for (int i = 0; i < 4; ++i) {
    const int rl = i * 16 + (tid >> 4);
    const int gr = brow + rl;
    if (gr >= M_ROWS) continue;
    const int c4 = (tid & 15) * 4;
    float4 v = *(const float4*)&csh[rl * 64 + c4];
    if (ADD_RES) {
      float4 q = ld4(RES + (size_t)gr * 256 + bcol + c4);
      v.x += q.x; v.y += q.y; v.z += q.z; v.w += q.w;
    }
    if (OUT_MODE == 0) {
      *(float4*)&((float*)Cv)[(size_t)gr * N + bcol + c4] = v;
    } else {
      ushort4 pk = make_ushort4(f2bf(v.x), f2bf(v.y), f2bf(v.z), f2bf(v.w));
      *(ushort4*)&((unsigned short*)Cv)[(size_t)gr * N + bcol + c4] = pk;
    }
  }
}

// ---- deformable sampling, head-partitioned for per-XCD L2 residency ----
__global__ __launch_bounds__(256) void msda5(
    const unsigned short* __restrict__ v, const unsigned short* __restrict__ oa,
    const float* __restrict__ ref, unsigned short* __restrict__ attout)
{
  constexpr int LW[4] = {100, 50, 25, 13};
  constexpr int LS[4] = {0, 10000, 12500, 13125};

  __shared__ int4   sidx[64][16];
  __shared__ float4 swt [64][16];

  const int bid   = blockIdx.x;
  const int h     = bid & 7;
  const int chunk = bid >> 3;
  const int tid   = threadIdx.x;
  const int qi    = tid >> 2;
  const int lq    = tid & 3;
  const int bq    = chunk * 64 + qi;
  const bool active = bq < M_ROWS;
  const int b     = (bq >= NQ) ? 1 : 0;
  const int pmask = qi & 7;

  if (active) {
    const int l = lq;
    const int W = LW[l];
    const float fD = (float)W;
    const unsigned short* oarow = oa + (size_t)bq * 384;

    uint2 lg = *(const uint2*)(oarow + 256 + h * 16 + l * 4);
    float g0 = bfu_lo(lg.x), g1 = bfu_hi(lg.x), g2 = bfu_lo(lg.y), g3 = bfu_hi(lg.y);
    float mx = fmaxf(fmaxf(g0, g1), fmaxf(g2, g3));
    mx = fmaxf(mx, __shfl_xor(mx, 1));
    mx = fmaxf(mx, __shfl_xor(mx, 2));
    float e0 = __expf(g0-mx), e1 = __expf(g1-mx), e2 = __expf(g2-mx), e3 = __expf(g3-mx);
    float s = e0 + e1 + e2 + e3;
    s += __shfl_xor(s, 1);
    s += __shfl_xor(s, 2);
    const float inv = 1.f / s;
    const float ee[4] = {e0*inv, e1*inv, e2*inv, e3*inv};

    uint4 ov = *(const uint4*)(oarow + h * 32 + l * 8);
    const float oxy[8] = {bfu_lo(ov.x), bfu_hi(ov.x), bfu_lo(ov.y), bfu_hi(ov.y),
                          bfu_lo(ov.z), bfu_hi(ov.z), bfu_lo(ov.w), bfu_hi(ov.w)};
    const float rx = ref[(size_t)bq * 8 + l * 2];
    const float ry = ref[(size_t)bq * 8 + l * 2 + 1];
    const int rowbase = b * NV + LS[l];

    #pragma unroll
    for (int j = 0; j < 4; ++j) {
      const float x = (rx + oxy[2*j]   / fD) * fD - 0.5f;
      const float y = (ry + oxy[2*j+1] / fD) * fD - 0.5f;
      const float x0f = floorf(x), y0f = floorf(y);
      const float lx = x - x0f, ly = y - y0f;
      const int x0 = (int)x0f, y0 = (int)y0f;
      const int x1 = x0 + 1,  y1 = y0 + 1;
      const int cx0 = min(max(x0, 0), W - 1), cx1 = min(max(x1, 0), W - 1);
      const int cy0 = min(max(y0, 0), W - 1), cy1 = min(max(y1, 0), W - 1);
      const float f00 = (x0 >= 0 && x0 < W && y0 >= 0 && y0 < W) ? 1.f : 0.f;
      const float f10 = (x1 >= 0 && x1 < W && y0 >= 0 && y0 < W) ? 1.f : 0.f;
      const float f01 = (x0 >= 0 && x0 < W && y1 >= 0 && y1 < W) ? 1.f : 0.f;
      const float f11 = (x1 >= 0 && x1 < W && y1 >= 0 && y1 < W) ? 1.f : 0.f;
      const float wt = ee[j];
      const int pi = (l * 4 + j) ^ pmask;
      sidx[qi][pi] = make_int4((rowbase + cy0 * W + cx0) * 64,
                               (rowbase + cy0 * W + cx1) * 64,
                               (rowbase + cy1 * W + cx0) * 64,
                               (rowbase + cy1 * W + cx1) * 64);
      swt[qi][pi] = make_float4(wt * (1.f - lx) * (1.f - ly) * f00,
                                wt * lx * (1.f - ly) * f10,
                                wt * (1.f - lx) * ly * f01,
                                wt * lx * ly * f11);
    }
  }
  __syncthreads();

  if (active) {
    const char* vb = (const char*)v + (size_t)h * M_ROWS * 64 + lq * 16;
    float acc[8] = {0.f, 0.f, 0.f, 0.f, 0.f, 0.f, 0.f, 0.f};
    #pragma unroll
    for (int p = 0; p < 16; ++p) {
      const int4   ix = sidx[qi][p ^ pmask];
      const float4 w4 = swt[qi][p ^ pmask];
      uint4 c0 = *(const uint4*)(vb + ix.x);
      uint4 c1 = *(const uint4*)(vb + ix.y);
      uint4 c2 = *(const uint4*)(vb + ix.z);
      uint4 c3 = *(const uint4*)(vb + ix.w);
      acc[0] = fmaf(w4.x, bfu_lo(c0.x), acc[0]); acc[1] = fmaf(w4.x, bfu_hi(c0.x), acc[1]);
      acc[2] = fmaf(w4.x, bfu_lo(c0.y), acc[2]); acc[3] = fmaf(w4.x, bfu_hi(c0.y), acc[3]);
      acc[4] = fmaf(w4.x, bfu_lo(c0.z), acc[4]); acc[5] = fmaf(w4.x, bfu_hi(c0.z), acc[5]);
      acc[6] = fmaf(w4.x, bfu_lo(c0.w), acc[6]); acc[7] = fmaf(w4.x, bfu_hi(c0.w), acc[7]);
      acc[0] = fmaf(w4.y, bfu_lo(c1.x), acc[0]); acc[1] = fmaf(w4.y, bfu_hi(c1.x), acc[1]);
      acc[2] = fmaf(w4.y, bfu_lo(c1.y), acc[2]); acc[3] = fmaf(w4.y, bfu_hi(c1.y), acc[3]);
      acc[4] = fmaf(w4.y, bfu_lo(c1.z), acc[4]); acc[5] = fmaf(w4.y, bfu_hi(c1.z), acc[5]);
      acc[6] = fmaf(w4.y, bfu_lo(c1.w), acc[6]); acc[7] = fmaf(w4.y, bfu_hi(c1.w), acc[7]);
      acc[0] = fmaf(w4.z, bfu_lo(c2.x), acc[0]); acc[1] = fmaf(w4.z, bfu_hi(c2.x), acc[1]);
      acc[2] = fmaf(w4.z, bfu_lo(c2.y), acc[2]); acc[3] = fmaf(w4.z, bfu_hi(c2.y), acc[3]);
      acc[4] = fmaf(w4.z, bfu_lo(c2.z), acc[4]); acc[5] = fmaf(w4.z, bfu_hi(c2.z), acc[5]);
      acc[6] = fmaf(w4.z, bfu_lo(c2.w), acc[6]); acc[7] = fmaf(w4.z, bfu_hi(c2.w), acc[7]);
      acc[0] = fmaf(w4.w, bfu_lo(c3.x), acc[0]); acc[1] = fmaf(w4.w, bfu_hi(c3.x), acc[1]);
      acc[2] = fmaf(w4.w, bfu_lo(c3.y), acc[2]); acc[3] = fmaf(w4.w, bfu_hi(c3.y), acc[3]);
      acc[4] = fmaf(w4.w, bfu_lo(c3.z), acc[4]); acc[5] = fmaf(w4.w, bfu_hi(c3.z), acc[5]);
      acc[6] = fmaf(w4.w, bfu_lo(c3.w), acc[6]); acc[7] = fmaf(w4.w, bfu_hi(c3.w), acc[7]);
    }
    uint4 pk;
    pk.x = pk2(acc[0], acc[1]);
    pk.y = pk2(acc[2], acc[3]);
    pk.z = pk2(acc[4], acc[5]);
    pk.w = pk2(acc[6], acc[7]);
    *(uint4*)(attout + (size_t)bq * 256 + h * 32 + lq * 8) = pk;
  }
}

extern "C" void kernel_launch(void* const* d_in, const int* in_sizes, int n_in,
                              void* d_out, int out_size, void* d_ws, size_t ws_size,
                              hipStream_t stream) {
  const float* query  = (const float*)d_in[0];
  const float* value  = (const float*)d_in[2];
  const float* qpos   = (const float*)d_in[3];
  const float* refpts = (const float*)d_in[4];
  const float* W_value = (const float*)d_in[8];
  const float* b_value = (const float*)d_in[9];
  const float* W_off   = (const float*)d_in[10];
  const float* b_off   = (const float*)d_in[11];
  const float* W_attn  = (const float*)d_in[12];
  const float* b_attn  = (const float*)d_in[13];
  const float* W_out   = (const float*)d_in[14];
  const float* b_out   = (const float*)d_in[15];
  const float* W_ffn   = (const float*)d_in[16];
  const float* b_ffn   = (const float*)d_in[17];
  float* out = (float*)d_out;

  // workspace layout (~48 MB)
  unsigned short* oa    = (unsigned short*)d_ws;            // (MP,384) bf16
  unsigned short* vbuf2 = oa + (size_t)MP * 384;            // [8][M_ROWS][32] bf16
  unsigned short* AB1   = vbuf2 + (size_t)8 * M_ROWS * 32;  // attout bf16
  unsigned short* AB2   = AB1 + (size_t)MP * 256;           // tmp bf16
  unsigned short* wts   = AB2 + (size_t)MP * 256;
  unsigned short* wv_t  = wts;
  unsigned short* woa_t = wts + 65536;   // [W_off^T ; W_attn^T]
  unsigned short* wu_t  = wts + 163840;
  unsigned short* wf_t  = wts + 229376;

  const dim3 blk(256);

  prep_w<<<dim3(1152), blk, 0, stream>>>(W_value, W_off, W_attn, W_out, W_ffn, wts);

  // merged: v-GEMM (head-split bf16) + oa-GEMM (bf16, M x 384)
  gemm_voa<<<dim3(1664 + 2496), blk, 0, stream>>>(
      value, query, qpos, wv_t, woa_t, b_value, b_off, b_attn, vbuf2, oa);
  // deformable sampling -> attout bf16
  msda5<<<dim3(8 * 416), blk, 0, stream>>>(vbuf2, oa, refpts, AB1);
  // tmp = attout @ W_out + b_out + query (residual) -> bf16
  gemm_gl<4,1,true><<<dim3(1664), blk, 0, stream>>>(
      AB1, wu_t, b_out, query, AB2, 256);
  // out = tmp @ W_ffn + b_ffn -> f32
  gemm_gl<4,0,false><<<dim3(1664), blk, 0, stream>>>(
      AB2, wf_t, b_ffn, nullptr, (void*)out, 256);
}

// Round 11
// 123.189 us; speedup vs baseline: 1.0848x; 1.0848x over previous
//
#include <hip/hip_runtime.h>
#include <hip/hip_bf16.h>
#include <math.h>

#define NQ 13294
#define NV 13294
#define M_ROWS (2*NQ)     // 26588
#define MP 26624          // padded row count (416*64)

typedef __attribute__((ext_vector_type(8))) short bf16x8;
typedef __attribute__((ext_vector_type(4))) float f32x4;
typedef __attribute__((ext_vector_type(2))) float f32x2;

__device__ __forceinline__ float4 ld4(const float* p){ return *(const float4*)p; }
__device__ __forceinline__ float bfu_lo(unsigned int u){ return __uint_as_float(u << 16); }
__device__ __forceinline__ float bfu_hi(unsigned int u){ return __uint_as_float(u & 0xffff0000u); }
__device__ __forceinline__ f32x2 up2(unsigned int u){
  return (f32x2){__uint_as_float(u << 16), __uint_as_float(u & 0xffff0000u)};
}
__device__ __forceinline__ unsigned short f2bf(float f){
  unsigned int u = __float_as_uint(f);
  u += 0x7fffu + ((u >> 16) & 1u);   // RNE
  return (unsigned short)(u >> 16);
}
__device__ __forceinline__ unsigned int pk2(float a, float b){
  return (unsigned int)f2bf(a) | ((unsigned int)f2bf(b) << 16);
}
__device__ __forceinline__ void gl_lds16(const unsigned short* g, unsigned short* l) {
  __builtin_amdgcn_global_load_lds(
      (const __attribute__((address_space(1))) unsigned int*)g,
      (__attribute__((address_space(3))) unsigned int*)l, 16, 0, 0);
}

// ---- prep: value->bf16, (query+qpos)->bf16 (zero-padded), + 5 weight transposes ----
__global__ __launch_bounds__(256) void prep_all(
    const float* __restrict__ value, const float* __restrict__ query,
    const float* __restrict__ qpos,
    unsigned short* __restrict__ val_bf, unsigned short* __restrict__ q_bf,
    const float* __restrict__ wv, const float* __restrict__ wo,
    const float* __restrict__ wa, const float* __restrict__ wu,
    const float* __restrict__ wf, unsigned short* __restrict__ wt)
{
  const int total = MP * 64;   // float4 groups
  for (int i = blockIdx.x * 256 + threadIdx.x; i < total; i += gridDim.x * 256) {
    const int e = i * 4;
    ushort4 a = make_ushort4(0,0,0,0), b = make_ushort4(0,0,0,0);
    if (e < M_ROWS * 256) {
      float4 v4 = ld4(value + e);
      a = make_ushort4(f2bf(v4.x), f2bf(v4.y), f2bf(v4.z), f2bf(v4.w));
      float4 q4 = ld4(query + e);
      float4 p4 = ld4(qpos + e);
      b = make_ushort4(f2bf(q4.x+p4.x), f2bf(q4.y+p4.y), f2bf(q4.z+p4.z), f2bf(q4.w+p4.w));
    }
    *(ushort4*)(val_bf + e) = a;
    *(ushort4*)(q_bf   + e) = b;
  }
  for (int t = blockIdx.x * 256 + threadIdx.x; t < 294912; t += gridDim.x * 256) {
    const float* src; int Nn; int base;
    if      (t < 65536)  { src = wv; Nn = 256; base = 0; }
    else if (t < 131072) { src = wo; Nn = 256; base = 65536; }
    else if (t < 163840) { src = wa; Nn = 128; base = 131072; }
    else if (t < 229376) { src = wu; Nn = 256; base = 163840; }
    else                 { src = wf; Nn = 256; base = 229376; }
    const int local = t - base;
    const int n = local >> 8, k = local & 255;
    wt[t] = f2bf(src[k * Nn + n]);
  }
}

// ---- 64x64-tile bf16 MFMA GEMM, full-K LDS via global_load_lds ----
// OUT_MODE: 0 = f32 rows, 1 = bf16 rows, 2 = bf16 head-split vbuf2[head][row][32]
template<int NCOL, int OUT_MODE, bool ADD_RES>
__global__ __launch_bounds__(256) void gemm_gl(
    const unsigned short* __restrict__ A, const unsigned short* __restrict__ Bt,
    const float* __restrict__ biasA, const float* __restrict__ biasB,
    const float* __restrict__ RES, void* __restrict__ Cv, int N)
{
  __shared__ unsigned short lds[32768];   // As [0,16384) | Bs [16384,32768)

  const int nwg = 416 * NCOL;             // divisible by 8
  const int lin = blockIdx.x;
  const int swz = (lin & 7) * (nwg >> 3) + (lin >> 3);
  const int brow = (swz / NCOL) * 64;
  const int bcol = (swz % NCOL) * 64;

  const int tid  = threadIdx.x;
  const int wid  = tid >> 6, lane = tid & 63;
  const int wr   = wid >> 1, wc = wid & 1;
  const int fr   = lane & 15, fg = lane >> 4;

  {
    const int r0   = lane >> 3;      // 0..7
    const int slot = lane & 7;       // 16B slot
    #pragma unroll
    for (int t = 0; t < 4; ++t) {
      #pragma unroll
      for (int c = 0; c < 2; ++c) {
        const int row = (wid * 2 + c) * 8 + r0;     // 0..63
        const int gsl = slot ^ (row & 7);
        gl_lds16(A  + (size_t)(brow + row) * 256 + t * 64 + (gsl << 3),
                 &lds[t * 4096 + (wid * 2 + c) * 512]);
        gl_lds16(Bt + (size_t)(bcol + row) * 256 + t * 64 + (gsl << 3),
                 &lds[16384 + t * 4096 + (wid * 2 + c) * 512]);
      }
    }
  }
  __syncthreads();

  f32x4 acc[2][2];
  #pragma unroll
  for (int m = 0; m < 2; ++m)
    #pragma unroll
    for (int n = 0; n < 2; ++n)
      acc[m][n] = (f32x4){0.f, 0.f, 0.f, 0.f};

  #pragma unroll
  for (int t = 0; t < 4; ++t) {
    const char* as = (const char*)&lds[t * 4096];
    const char* bs = (const char*)&lds[16384 + t * 4096];
    #pragma unroll
    for (int kk = 0; kk < 2; ++kk) {
      const int kb = kk * 64 + fg * 16;
      bf16x8 af[2], bfv[2];
      #pragma unroll
      for (int m = 0; m < 2; ++m) {
        const int r = wr * 32 + m * 16 + fr;
        af[m] = *(const bf16x8*)(as + r * 128 + (kb ^ ((r & 7) << 4)));
      }
      #pragma unroll
      for (int n = 0; n < 2; ++n) {
        const int r = wc * 32 + n * 16 + fr;
        bfv[n] = *(const bf16x8*)(bs + r * 128 + (kb ^ ((r & 7) << 4)));
      }
      #pragma unroll
      for (int m = 0; m < 2; ++m)
        #pragma unroll
        for (int n = 0; n < 2; ++n)
          acc[m][n] = __builtin_amdgcn_mfma_f32_16x16x32_bf16(af[m], bfv[n], acc[m][n], 0, 0, 0);
    }
  }

  // ---- epilogue: acc -> LDS (f32 64x64) -> coalesced stores ----
  __syncthreads();
  float* csh = (float*)lds;
  const int c0 = bcol + wc * 32 + fr;
  const int c1 = c0 + 16;
  const float bn0 = (c0 < 256) ? biasA[c0] : biasB[c0 - 256];
  const float bn1 = (c1 < 256) ? biasA[c1] : biasB[c1 - 256];
  #pragma unroll
  for (int m = 0; m < 2; ++m)
    #pragma unroll
    for (int j = 0; j < 4; ++j) {
      const int row = wr * 32 + m * 16 + fg * 4 + j;
      csh[row * 64 + wc * 32 + fr]      = acc[m][0][j] + bn0;
      csh[row * 64 + wc * 32 + 16 + fr] = acc[m][1][j] + bn1;
    }
  __syncthreads();
  #pragma unroll
  for (int i = 0; i < 4; ++i) {
    const int rl = i * 16 + (tid >> 4);
    const int gr = brow + rl;
    if (gr >= M_ROWS) continue;
    const int c4 = (tid & 15) * 4;
    float4 v = *(const float4*)&csh[rl * 64 + c4];
    if (ADD_RES) {
      float4 q = ld4(RES + (size_t)gr * 256 + bcol + c4);
      v.x += q.x; v.y += q.y; v.z += q.z; v.w += q.w;
    }
    if (OUT_MODE == 0) {
      *(float4*)&((float*)Cv)[(size_t)gr * N + bcol + c4] = v;
    } else if (OUT_MODE == 1) {
      ushort4 pk = make_ushort4(f2bf(v.x), f2bf(v.y), f2bf(v.z), f2bf(v.w));
      *(ushort4*)&((unsigned short*)Cv)[(size_t)gr * N + bcol + c4] = pk;
    } else {
      const int head = (bcol + c4) >> 5;
      const int ch   = c4 & 31;
      ushort4 pk = make_ushort4(f2bf(v.x), f2bf(v.y), f2bf(v.z), f2bf(v.w));
      *(ushort4*)&((unsigned short*)Cv)[((size_t)head * M_ROWS + gr) * 32 + ch] = pk;
    }
  }
}

// ---- deformable sampling, head-partitioned for per-XCD L2 residency ----
// v: [8][M_ROWS][32] bf16 head-major; oa: [M][384] bf16 (off 0:256 | logits 256:384)
__global__ __launch_bounds__(256) void msda5(
    const unsigned short* __restrict__ v, const unsigned short* __restrict__ oa,
    const float* __restrict__ ref, unsigned short* __restrict__ attout)
{
  constexpr int LW[4] = {100, 50, 25, 13};
  constexpr int LS[4] = {0, 10000, 12500, 13125};

  __shared__ int4   sidx[64][16];
  __shared__ float4 swt [64][16];

  const int bid   = blockIdx.x;
  const int h     = bid & 7;          // head == XCD under %8 round-robin
  const int chunk = bid >> 3;
  const int tid   = threadIdx.x;
  const int qi    = tid >> 2;
  const int lq    = tid & 3;
  const int bq    = chunk * 64 + qi;
  const bool active = bq < M_ROWS;
  const int b     = (bq >= NQ) ? 1 : 0;
  const int pmask = qi & 7;

  if (active) {
    const int l = lq;
    const int W = LW[l];
    const float fD = (float)W;
    const unsigned short* oarow = oa + (size_t)bq * 384;

    uint2 lg = *(const uint2*)(oarow + 256 + h * 16 + l * 4);
    float g0 = bfu_lo(lg.x), g1 = bfu_hi(lg.x), g2 = bfu_lo(lg.y), g3 = bfu_hi(lg.y);
    float mx = fmaxf(fmaxf(g0, g1), fmaxf(g2, g3));
    mx = fmaxf(mx, __shfl_xor(mx, 1));
    mx = fmaxf(mx, __shfl_xor(mx, 2));
    float e0 = __expf(g0-mx), e1 = __expf(g1-mx), e2 = __expf(g2-mx), e3 = __expf(g3-mx);
    float s = e0 + e1 + e2 + e3;
    s += __shfl_xor(s, 1);
    s += __shfl_xor(s, 2);
    const float inv = 1.f / s;
    const float ee[4] = {e0*inv, e1*inv, e2*inv, e3*inv};

    uint4 ov = *(const uint4*)(oarow + h * 32 + l * 8);
    const float oxy[8] = {bfu_lo(ov.x), bfu_hi(ov.x), bfu_lo(ov.y), bfu_hi(ov.y),
                          bfu_lo(ov.z), bfu_hi(ov.z), bfu_lo(ov.w), bfu_hi(ov.w)};
    const float rx = ref[(size_t)bq * 8 + l * 2];
    const float ry = ref[(size_t)bq * 8 + l * 2 + 1];
    const int rowbase = b * NV + LS[l];

    #pragma unroll
    for (int j = 0; j < 4; ++j) {
      // (rx + ox/W)*W - 0.5 == rx*W + ox - 0.5  (kills 2 f32 divides per point)
      const float x = fmaf(rx, fD, oxy[2*j])   - 0.5f;
      const float y = fmaf(ry, fD, oxy[2*j+1]) - 0.5f;
      const float x0f = floorf(x), y0f = floorf(y);
      const float lx = x - x0f, ly = y - y0f;
      const int x0 = (int)x0f, y0 = (int)y0f;
      const int x1 = x0 + 1,  y1 = y0 + 1;
      const int cx0 = min(max(x0, 0), W - 1), cx1 = min(max(x1, 0), W - 1);
      const int cy0 = min(max(y0, 0), W - 1), cy1 = min(max(y1, 0), W - 1);
      const float f00 = (x0 >= 0 && x0 < W && y0 >= 0 && y0 < W) ? 1.f : 0.f;
      const float f10 = (x1 >= 0 && x1 < W && y0 >= 0 && y0 < W) ? 1.f : 0.f;
      const float f01 = (x0 >= 0 && x0 < W && y1 >= 0 && y1 < W) ? 1.f : 0.f;
      const float f11 = (x1 >= 0 && x1 < W && y1 >= 0 && y1 < W) ? 1.f : 0.f;
      const float wt = ee[j];
      const int pi = (l * 4 + j) ^ pmask;
      sidx[qi][pi] = make_int4((rowbase + cy0 * W + cx0) * 64,
                               (rowbase + cy0 * W + cx1) * 64,
                               (rowbase + cy1 * W + cx0) * 64,
                               (rowbase + cy1 * W + cx1) * 64);
      swt[qi][pi] = make_float4(wt * (1.f - lx) * (1.f - ly) * f00,
                                wt * lx * (1.f - ly) * f10,
                                wt * (1.f - lx) * ly * f01,
                                wt * lx * ly * f11);
    }
  }
  __syncthreads();

  if (active) {
    const char* vb = (const char*)v + (size_t)h * M_ROWS * 64 + lq * 16;
    f32x2 acc2[4];
    #pragma unroll
    for (int k = 0; k < 4; ++k) acc2[k] = (f32x2){0.f, 0.f};
    #pragma unroll
    for (int p = 0; p < 16; ++p) {
      const int4   ix = sidx[qi][p ^ pmask];
      const float4 w4 = swt[qi][p ^ pmask];
      uint4 c0 = *(const uint4*)(vb + ix.x);
      uint4 c1 = *(const uint4*)(vb + ix.y);
      uint4 c2 = *(const uint4*)(vb + ix.z);
      uint4 c3 = *(const uint4*)(vb + ix.w);
      const f32x2 w0 = (f32x2){w4.x, w4.x};
      const f32x2 w1 = (f32x2){w4.y, w4.y};
      const f32x2 w2 = (f32x2){w4.z, w4.z};
      const f32x2 w3 = (f32x2){w4.w, w4.w};
      // packed f32 fma: 16 v_pk_fma_f32 per point (vs 32 scalar v_fma)
      acc2[0] = w0 * up2(c0.x) + acc2[0];
      acc2[1] = w0 * up2(c0.y) + acc2[1];
      acc2[2] = w0 * up2(c0.z) + acc2[2];
      acc2[3] = w0 * up2(c0.w) + acc2[3];
      acc2[0] = w1 * up2(c1.x) + acc2[0];
      acc2[1] = w1 * up2(c1.y) + acc2[1];
      acc2[2] = w1 * up2(c1.z) + acc2[2];
      acc2[3] = w1 * up2(c1.w) + acc2[3];
      acc2[0] = w2 * up2(c2.x) + acc2[0];
      acc2[1] = w2 * up2(c2.y) + acc2[1];
      acc2[2] = w2 * up2(c2.z) + acc2[2];
      acc2[3] = w2 * up2(c2.w) + acc2[3];
      acc2[0] = w3 * up2(c3.x) + acc2[0];
      acc2[1] = w3 * up2(c3.y) + acc2[1];
      acc2[2] = w3 * up2(c3.z) + acc2[2];
      acc2[3] = w3 * up2(c3.w) + acc2[3];
    }
    uint4 pk;
    pk.x = pk2(acc2[0][0], acc2[0][1]);
    pk.y = pk2(acc2[1][0], acc2[1][1]);
    pk.z = pk2(acc2[2][0], acc2[2][1]);
    pk.w = pk2(acc2[3][0], acc2[3][1]);
    *(uint4*)(attout + (size_t)bq * 256 + h * 32 + lq * 8) = pk;
  }
}

extern "C" void kernel_launch(void* const* d_in, const int* in_sizes, int n_in,
                              void* d_out, int out_size, void* d_ws, size_t ws_size,
                              hipStream_t stream) {
  const float* query  = (const float*)d_in[0];
  const float* value  = (const float*)d_in[2];
  const float* qpos   = (const float*)d_in[3];
  const float* refpts = (const float*)d_in[4];
  const float* W_value = (const float*)d_in[8];
  const float* b_value = (const float*)d_in[9];
  const float* W_off   = (const float*)d_in[10];
  const float* b_off   = (const float*)d_in[11];
  const float* W_attn  = (const float*)d_in[12];
  const float* b_attn  = (const float*)d_in[13];
  const float* W_out   = (const float*)d_in[14];
  const float* b_out   = (const float*)d_in[15];
  const float* W_ffn   = (const float*)d_in[16];
  const float* b_ffn   = (const float*)d_in[17];
  float* out = (float*)d_out;

  // workspace layout (~62 MB)
  unsigned short* oa    = (unsigned short*)d_ws;          // (MP,384) bf16
  unsigned short* vbuf2 = oa + (size_t)MP * 384;          // [8][M_ROWS][32] bf16
  unsigned short* AB1   = vbuf2 + (size_t)8 * M_ROWS * 32; // val_bf -> attout bf16
  unsigned short* AB2   = AB1 + (size_t)MP * 256;         // q_bf -> tmp bf16
  unsigned short* wts   = AB2 + (size_t)MP * 256;
  unsigned short* wv_t  = wts;
  unsigned short* woa_t = wts + 65536;   // [W_off^T ; W_attn^T]
  unsigned short* wu_t  = wts + 163840;
  unsigned short* wf_t  = wts + 229376;

  const dim3 blk(256);

  prep_all<<<dim3(2048), blk, 0, stream>>>(value, query, qpos, AB1, AB2,
      W_value, W_off, W_attn, W_out, W_ffn, wts);

  // v = value @ W_value + b -> vbuf2 head-split bf16
  gemm_gl<4,2,false><<<dim3(1664), blk, 0, stream>>>(
      AB1, wv_t, b_value, b_value, nullptr, vbuf2, 256);
  // [off | attn] = (q+pos) @ [W_off;W_attn] + biases -> bf16 (M,384)
  gemm_gl<6,1,false><<<dim3(2496), blk, 0, stream>>>(
      AB2, woa_t, b_off, b_attn, nullptr, oa, 384);
  // deformable sampling -> attout bf16 (overwrites AB1)
  msda5<<<dim3(8 * 416), blk, 0, stream>>>(vbuf2, oa, refpts, AB1);
  // tmp = attout @ W_out + b_out + query -> bf16 (overwrites AB2)
  gemm_gl<4,1,true><<<dim3(1664), blk, 0, stream>>>(
      AB1, wu_t, b_out, b_out, query, AB2, 256);
  // out = tmp @ W_ffn + b_ffn -> f32
  gemm_gl<4,0,false><<<dim3(1664), blk, 0, stream>>>(
      AB2, wf_t, b_ffn, b_ffn, nullptr, (void*)out, 256);
}

// Round 12
// 120.923 us; speedup vs baseline: 1.1051x; 1.0187x over previous
//
#include <hip/hip_runtime.h>
#include <hip/hip_bf16.h>
#include <math.h>

#define NQ 13294
#define NV 13294
#define M_ROWS (2*NQ)     // 26588
#define MP 26624          // padded row count (416*64)

typedef __attribute__((ext_vector_type(8))) short bf16x8;
typedef __attribute__((ext_vector_type(4))) float f32x4;
typedef __attribute__((ext_vector_type(2))) float f32x2;

__device__ __forceinline__ float4 ld4(const float* p){ return *(const float4*)p; }
__device__ __forceinline__ float bfu_lo(unsigned int u){ return __uint_as_float(u << 16); }
__device__ __forceinline__ float bfu_hi(unsigned int u){ return __uint_as_float(u & 0xffff0000u); }
__device__ __forceinline__ f32x2 up2(unsigned int u){
  return (f32x2){__uint_as_float(u << 16), __uint_as_float(u & 0xffff0000u)};
}
__device__ __forceinline__ unsigned short f2bf(float f){
  unsigned int u = __float_as_uint(f);
  u += 0x7fffu + ((u >> 16) & 1u);   // RNE
  return (unsigned short)(u >> 16);
}
__device__ __forceinline__ unsigned int pk2(float a, float b){
  return (unsigned int)f2bf(a) | ((unsigned int)f2bf(b) << 16);
}
__device__ __forceinline__ void gl_lds16(const unsigned short* g, unsigned short* l) {
  __builtin_amdgcn_global_load_lds(
      (const __attribute__((address_space(1))) unsigned int*)g,
      (__attribute__((address_space(3))) unsigned int*)l, 16, 0, 0);
}

// ---- prep: value->bf16, (query+qpos)->bf16 (zero-padded), + 5 weight transposes ----
__global__ __launch_bounds__(256) void prep_all(
    const float* __restrict__ value, const float* __restrict__ query,
    const float* __restrict__ qpos,
    unsigned short* __restrict__ val_bf, unsigned short* __restrict__ q_bf,
    const float* __restrict__ wv, const float* __restrict__ wo,
    const float* __restrict__ wa, const float* __restrict__ wu,
    const float* __restrict__ wf, unsigned short* __restrict__ wt)
{
  const int total = MP * 64;   // float4 groups
  for (int i = blockIdx.x * 256 + threadIdx.x; i < total; i += gridDim.x * 256) {
    const int e = i * 4;
    ushort4 a = make_ushort4(0,0,0,0), b = make_ushort4(0,0,0,0);
    if (e < M_ROWS * 256) {
      float4 v4 = ld4(value + e);
      a = make_ushort4(f2bf(v4.x), f2bf(v4.y), f2bf(v4.z), f2bf(v4.w));
      float4 q4 = ld4(query + e);
      float4 p4 = ld4(qpos + e);
      b = make_ushort4(f2bf(q4.x+p4.x), f2bf(q4.y+p4.y), f2bf(q4.z+p4.z), f2bf(q4.w+p4.w));
    }
    *(ushort4*)(val_bf + e) = a;
    *(ushort4*)(q_bf   + e) = b;
  }
  for (int t = blockIdx.x * 256 + threadIdx.x; t < 294912; t += gridDim.x * 256) {
    const float* src; int Nn; int base;
    if      (t < 65536)  { src = wv; Nn = 256; base = 0; }
    else if (t < 131072) { src = wo; Nn = 256; base = 65536; }
    else if (t < 163840) { src = wa; Nn = 128; base = 131072; }
    else if (t < 229376) { src = wu; Nn = 256; base = 163840; }
    else                 { src = wf; Nn = 256; base = 229376; }
    const int local = t - base;
    const int n = local >> 8, k = local & 255;
    wt[t] = f2bf(src[k * Nn + n]);
  }
}

// ---- 64x64-tile bf16 MFMA GEMM, full-K LDS via global_load_lds ----
// OUT_MODE: 0 = f32 rows, 1 = bf16 rows, 2 = bf16 head-split vbuf2[head][row][32]
template<int NCOL, int OUT_MODE, bool ADD_RES>
__global__ __launch_bounds__(256) void gemm_gl(
    const unsigned short* __restrict__ A, const unsigned short* __restrict__ Bt,
    const float* __restrict__ biasA, const float* __restrict__ biasB,
    const float* __restrict__ RES, void* __restrict__ Cv, int N)
{
  __shared__ unsigned short lds[32768];   // As [0,16384) | Bs [16384,32768)

  const int nwg = 416 * NCOL;             // divisible by 8
  const int lin = blockIdx.x;
  const int swz = (lin & 7) * (nwg >> 3) + (lin >> 3);
  const int brow = (swz / NCOL) * 64;
  const int bcol = (swz % NCOL) * 64;

  const int tid  = threadIdx.x;
  const int wid  = tid >> 6, lane = tid & 63;
  const int wr   = wid >> 1, wc = wid & 1;
  const int fr   = lane & 15, fg = lane >> 4;

  {
    const int r0   = lane >> 3;      // 0..7
    const int slot = lane & 7;       // 16B slot
    #pragma unroll
    for (int t = 0; t < 4; ++t) {
      #pragma unroll
      for (int c = 0; c < 2; ++c) {
        const int row = (wid * 2 + c) * 8 + r0;     // 0..63
        const int gsl = slot ^ (row & 7);
        gl_lds16(A  + (size_t)(brow + row) * 256 + t * 64 + (gsl << 3),
                 &lds[t * 4096 + (wid * 2 + c) * 512]);
        gl_lds16(Bt + (size_t)(bcol + row) * 256 + t * 64 + (gsl << 3),
                 &lds[16384 + t * 4096 + (wid * 2 + c) * 512]);
      }
    }
  }
  __syncthreads();

  f32x4 acc[2][2];
  #pragma unroll
  for (int m = 0; m < 2; ++m)
    #pragma unroll
    for (int n = 0; n < 2; ++n)
      acc[m][n] = (f32x4){0.f, 0.f, 0.f, 0.f};

  #pragma unroll
  for (int t = 0; t < 4; ++t) {
    const char* as = (const char*)&lds[t * 4096];
    const char* bs = (const char*)&lds[16384 + t * 4096];
    #pragma unroll
    for (int kk = 0; kk < 2; ++kk) {
      const int kb = kk * 64 + fg * 16;
      bf16x8 af[2], bfv[2];
      #pragma unroll
      for (int m = 0; m < 2; ++m) {
        const int r = wr * 32 + m * 16 + fr;
        af[m] = *(const bf16x8*)(as + r * 128 + (kb ^ ((r & 7) << 4)));
      }
      #pragma unroll
      for (int n = 0; n < 2; ++n) {
        const int r = wc * 32 + n * 16 + fr;
        bfv[n] = *(const bf16x8*)(bs + r * 128 + (kb ^ ((r & 7) << 4)));
      }
      #pragma unroll
      for (int m = 0; m < 2; ++m)
        #pragma unroll
        for (int n = 0; n < 2; ++n)
          acc[m][n] = __builtin_amdgcn_mfma_f32_16x16x32_bf16(af[m], bfv[n], acc[m][n], 0, 0, 0);
    }
  }

  // ---- epilogue: acc -> LDS (f32 64x64) -> coalesced stores ----
  __syncthreads();
  float* csh = (float*)lds;
  const int c0 = bcol + wc * 32 + fr;
  const int c1 = c0 + 16;
  const float bn0 = (c0 < 256) ? biasA[c0] : biasB[c0 - 256];
  const float bn1 = (c1 < 256) ? biasA[c1] : biasB[c1 - 256];
  #pragma unroll
  for (int m = 0; m < 2; ++m)
    #pragma unroll
    for (int j = 0; j < 4; ++j) {
      const int row = wr * 32 + m * 16 + fg * 4 + j;
      csh[row * 64 + wc * 32 + fr]      = acc[m][0][j] + bn0;
      csh[row * 64 + wc * 32 + 16 + fr] = acc[m][1][j] + bn1;
    }
  __syncthreads();
  #pragma unroll
  for (int i = 0; i < 4; ++i) {
    const int rl = i * 16 + (tid >> 4);
    const int gr = brow + rl;
    if (gr >= M_ROWS) continue;
    const int c4 = (tid & 15) * 4;
    float4 v = *(const float4*)&csh[rl * 64 + c4];
    if (ADD_RES) {
      float4 q = ld4(RES + (size_t)gr * 256 + bcol + c4);
      v.x += q.x; v.y += q.y; v.z += q.z; v.w += q.w;
    }
    if (OUT_MODE == 0) {
      *(float4*)&((float*)Cv)[(size_t)gr * N + bcol + c4] = v;
    } else if (OUT_MODE == 1) {
      ushort4 pk = make_ushort4(f2bf(v.x), f2bf(v.y), f2bf(v.z), f2bf(v.w));
      *(ushort4*)&((unsigned short*)Cv)[(size_t)gr * N + bcol + c4] = pk;
    } else {
      const int head = (bcol + c4) >> 5;
      const int ch   = c4 & 31;
      ushort4 pk = make_ushort4(f2bf(v.x), f2bf(v.y), f2bf(v.z), f2bf(v.w));
      *(ushort4*)&((unsigned short*)Cv)[((size_t)head * M_ROWS + gr) * 32 + ch] = pk;
    }
  }
}

// ---- deformable sampling v2: paired x-corners (128B loads), 8 lanes/(q,h) ----
// v: [8][M_ROWS][32] bf16 head-major; oa: [M][384] bf16 (off 0:256 | logits 256:384)
// Block = 32 queries x 1 head x 8 lanes; head = blockIdx&7 (XCD-affine).
// Lane c: corner-elem = c>>2 (x-pair element), channel-octet = c&3.
__global__ __launch_bounds__(256) void msda6(
    const unsigned short* __restrict__ v, const unsigned short* __restrict__ oa,
    const float* __restrict__ ref, unsigned short* __restrict__ attout)
{
  constexpr int LW[4] = {100, 50, 25, 13};
  constexpr int LS[4] = {0, 10000, 12500, 13125};

  __shared__ int2   sidx[32][17];   // [q][p] pair-base BYTE offsets (y0,y1); padded
  __shared__ float4 swt [32][17];   // [q][p] weights (y0e0, y0e1, y1e0, y1e1)

  const int bid   = blockIdx.x;
  const int h     = bid & 7;          // head == XCD under %8 round-robin
  const int chunk = bid >> 3;         // 0..830
  const int tid   = threadIdx.x;
  const int q     = tid >> 3;         // query in block 0..31
  const int c     = tid & 7;          // lane-in-group
  const int bq    = chunk * 32 + q;
  const bool active = bq < M_ROWS;
  const int b     = (bq >= NQ) ? 1 : 0;

  if (active) {
    // this thread owns points p = 2c, 2c+1 (both in level l = c>>1)
    const int l = c >> 1;
    const int W = LW[l];
    const float fD = (float)W;
    const unsigned short* oarow = oa + (size_t)bq * 384;

    // softmax over 16 logits, 2 per lane across 8 lanes
    unsigned int lgu = *(const unsigned int*)(oarow + 256 + h * 16 + c * 2);
    float g0 = bfu_lo(lgu), g1 = bfu_hi(lgu);
    float mx = fmaxf(g0, g1);
    mx = fmaxf(mx, __shfl_xor(mx, 1));
    mx = fmaxf(mx, __shfl_xor(mx, 2));
    mx = fmaxf(mx, __shfl_xor(mx, 4));
    float e0 = __expf(g0 - mx), e1 = __expf(g1 - mx);
    float s = e0 + e1;
    s += __shfl_xor(s, 1);
    s += __shfl_xor(s, 2);
    s += __shfl_xor(s, 4);
    const float inv = 1.f / s;
    const float wpt[2] = {e0 * inv, e1 * inv};

    // offsets for 2 points: 4 bf16 = 8B
    uint2 ou = *(const uint2*)(oarow + h * 32 + c * 4);
    const float oxy[4] = {bfu_lo(ou.x), bfu_hi(ou.x), bfu_lo(ou.y), bfu_hi(ou.y)};
    const float rx = ref[(size_t)bq * 8 + l * 2];
    const float ry = ref[(size_t)bq * 8 + l * 2 + 1];
    const int rowbase = b * NV + LS[l];

    #pragma unroll
    for (int j = 0; j < 2; ++j) {
      const float x = fmaf(rx, fD, oxy[2*j])   - 0.5f;
      const float y = fmaf(ry, fD, oxy[2*j+1]) - 0.5f;
      const float x0f = floorf(x), y0f = floorf(y);
      const float lx = x - x0f, ly = y - y0f;
      const int x0 = (int)x0f, y0 = (int)y0f;
      const int y1 = y0 + 1;
      const int xbase = min(max(x0, 0), W - 2);
      // route x-corner weights to pair elements (handles clamp/invalid exactly)
      const float wx0 = 1.f - lx, wx1 = lx;
      const float we0 = (x0 == xbase     ? wx0 : 0.f) + (x0 == xbase - 1 ? wx1 : 0.f);
      const float we1 = (x0 == xbase + 1 ? wx0 : 0.f) + (x0 == xbase     ? wx1 : 0.f);
      const int cy0 = min(max(y0, 0), W - 1), cy1 = min(max(y1, 0), W - 1);
      const float wy0 = (y0 >= 0 && y0 < W) ? (1.f - ly) : 0.f;
      const float wy1 = (y1 >= 0 && y1 < W) ? ly : 0.f;
      const float wt = wpt[j];
      const int p = c * 2 + j;
      sidx[q][p] = make_int2((rowbase + cy0 * W + xbase) * 64,
                             (rowbase + cy1 * W + xbase) * 64);
      swt[q][p] = make_float4(wt * wy0 * we0, wt * wy0 * we1,
                              wt * wy1 * we0, wt * wy1 * we1);
    }
  }
  __syncthreads();

  if (active) {
    const char* vb = (const char*)v + (size_t)h * M_ROWS * 64 + c * 16;
    const int el = c >> 2;   // which x-corner element this lane holds
    f32x2 acc2[4];
    #pragma unroll
    for (int k = 0; k < 4; ++k) acc2[k] = (f32x2){0.f, 0.f};
    #pragma unroll
    for (int p = 0; p < 16; ++p) {
      const int2   ix = sidx[q][p];
      const float4 w4 = swt[q][p];
      uint4 r0 = *(const uint4*)(vb + ix.x);   // y0 pair, my 16B
      uint4 r1 = *(const uint4*)(vb + ix.y);   // y1 pair, my 16B
      const float wa = el ? w4.y : w4.x;
      const float wb = el ? w4.w : w4.z;
      const f32x2 wav = (f32x2){wa, wa};
      const f32x2 wbv = (f32x2){wb, wb};
      acc2[0] = wav * up2(r0.x) + acc2[0];
      acc2[1] = wav * up2(r0.y) + acc2[1];
      acc2[2] = wav * up2(r0.z) + acc2[2];
      acc2[3] = wav * up2(r0.w) + acc2[3];
      acc2[0] = wbv * up2(r1.x) + acc2[0];
      acc2[1] = wbv * up2(r1.y) + acc2[1];
      acc2[2] = wbv * up2(r1.z) + acc2[2];
      acc2[3] = wbv * up2(r1.w) + acc2[3];
    }
    // merge the two x-corner halves (lanes c and c^4 hold same channels)
    #pragma unroll
    for (int k = 0; k < 4; ++k) {
      acc2[k][0] += __shfl_xor(acc2[k][0], 4);
      acc2[k][1] += __shfl_xor(acc2[k][1], 4);
    }
    if (c < 4) {
      uint4 pk;
      pk.x = pk2(acc2[0][0], acc2[0][1]);
      pk.y = pk2(acc2[1][0], acc2[1][1]);
      pk.z = pk2(acc2[2][0], acc2[2][1]);
      pk.w = pk2(acc2[3][0], acc2[3][1]);
      *(uint4*)(attout + (size_t)bq * 256 + h * 32 + c * 8) = pk;
    }
  }
}

extern "C" void kernel_launch(void* const* d_in, const int* in_sizes, int n_in,
                              void* d_out, int out_size, void* d_ws, size_t ws_size,
                              hipStream_t stream) {
  const float* query  = (const float*)d_in[0];
  const float* value  = (const float*)d_in[2];
  const float* qpos   = (const float*)d_in[3];
  const float* refpts = (const float*)d_in[4];
  const float* W_value = (const float*)d_in[8];
  const float* b_value = (const float*)d_in[9];
  const float* W_off   = (const float*)d_in[10];
  const float* b_off   = (const float*)d_in[11];
  const float* W_attn  = (const float*)d_in[12];
  const float* b_attn  = (const float*)d_in[13];
  const float* W_out   = (const float*)d_in[14];
  const float* b_out   = (const float*)d_in[15];
  const float* W_ffn   = (const float*)d_in[16];
  const float* b_ffn   = (const float*)d_in[17];
  float* out = (float*)d_out;

  // workspace layout (~62 MB)
  unsigned short* oa    = (unsigned short*)d_ws;          // (MP,384) bf16
  unsigned short* vbuf2 = oa + (size_t)MP * 384;          // [8][M_ROWS][32] bf16
  unsigned short* AB1   = vbuf2 + (size_t)8 * M_ROWS * 32; // val_bf -> attout bf16
  unsigned short* AB2   = AB1 + (size_t)MP * 256;         // q_bf -> tmp bf16
  unsigned short* wts   = AB2 + (size_t)MP * 256;
  unsigned short* wv_t  = wts;
  unsigned short* woa_t = wts + 65536;   // [W_off^T ; W_attn^T]
  unsigned short* wu_t  = wts + 163840;
  unsigned short* wf_t  = wts + 229376;

  const dim3 blk(256);

  prep_all<<<dim3(2048), blk, 0, stream>>>(value, query, qpos, AB1, AB2,
      W_value, W_off, W_attn, W_out, W_ffn, wts);

  // v = value @ W_value + b -> vbuf2 head-split bf16
  gemm_gl<4,2,false><<<dim3(1664), blk, 0, stream>>>(
      AB1, wv_t, b_value, b_value, nullptr, vbuf2, 256);
  // [off | attn] = (q+pos) @ [W_off;W_attn] + biases -> bf16 (M,384)
  gemm_gl<6,1,false><<<dim3(2496), blk, 0, stream>>>(
      AB2, woa_t, b_off, b_attn, nullptr, oa, 384);
  // deformable sampling -> attout bf16 (overwrites AB1)
  msda6<<<dim3(8 * 831), blk, 0, stream>>>(vbuf2, oa, refpts, AB1);
  // tmp = attout @ W_out + b_out + query -> bf16 (overwrites AB2)
  gemm_gl<4,1,true><<<dim3(1664), blk, 0, stream>>>(
      AB1, wu_t, b_out, b_out, query, AB2, 256);
  // out = tmp @ W_ffn + b_ffn -> f32
  gemm_gl<4,0,false><<<dim3(1664), blk, 0, stream>>>(
      AB2, wf_t, b_ffn, b_ffn, nullptr, (void*)out, 256);
}

// Round 13
// 112.742 us; speedup vs baseline: 1.1853x; 1.0726x over previous
//
#include <hip/hip_runtime.h>
#include <hip/hip_bf16.h>
#include <math.h>

#define NQ 13294
#define NV 13294
#define M_ROWS (2*NQ)     // 26588
#define MP 26624          // padded row count (416*64)

typedef __attribute__((ext_vector_type(8))) short bf16x8;
typedef __attribute__((ext_vector_type(4))) float f32x4;
typedef __attribute__((ext_vector_type(2))) float f32x2;

__device__ __forceinline__ float4 ld4(const float* p){ return *(const float4*)p; }
__device__ __forceinline__ float bfu_lo(unsigned int u){ return __uint_as_float(u << 16); }
__device__ __forceinline__ float bfu_hi(unsigned int u){ return __uint_as_float(u & 0xffff0000u); }
__device__ __forceinline__ unsigned short f2bf(float f){
  unsigned int u = __float_as_uint(f);
  u += 0x7fffu + ((u >> 16) & 1u);   // RNE
  return (unsigned short)(u >> 16);
}
__device__ __forceinline__ unsigned int pk2(float a, float b){
  return (unsigned int)f2bf(a) | ((unsigned int)f2bf(b) << 16);
}
__device__ __forceinline__ void gl_lds16(const unsigned short* g, unsigned short* l) {
  __builtin_amdgcn_global_load_lds(
      (const __attribute__((address_space(1))) unsigned int*)g,
      (__attribute__((address_space(3))) unsigned int*)l, 16, 0, 0);
}

// ---- prep: value->bf16, (query+qpos)->bf16 (zero-padded), + 5 weight transposes ----
__global__ __launch_bounds__(256) void prep_all(
    const float* __restrict__ value, const float* __restrict__ query,
    const float* __restrict__ qpos,
    unsigned short* __restrict__ val_bf, unsigned short* __restrict__ q_bf,
    const float* __restrict__ wv, const float* __restrict__ wo,
    const float* __restrict__ wa, const float* __restrict__ wu,
    const float* __restrict__ wf, unsigned short* __restrict__ wt)
{
  const int total = MP * 64;   // float4 groups
  for (int i = blockIdx.x * 256 + threadIdx.x; i < total; i += gridDim.x * 256) {
    const int e = i * 4;
    ushort4 a = make_ushort4(0,0,0,0), b = make_ushort4(0,0,0,0);
    if (e < M_ROWS * 256) {
      float4 v4 = ld4(value + e);
      a = make_ushort4(f2bf(v4.x), f2bf(v4.y), f2bf(v4.z), f2bf(v4.w));
      float4 q4 = ld4(query + e);
      float4 p4 = ld4(qpos + e);
      b = make_ushort4(f2bf(q4.x+p4.x), f2bf(q4.y+p4.y), f2bf(q4.z+p4.z), f2bf(q4.w+p4.w));
    }
    *(ushort4*)(val_bf + e) = a;
    *(ushort4*)(q_bf   + e) = b;
  }
  for (int t = blockIdx.x * 256 + threadIdx.x; t < 294912; t += gridDim.x * 256) {
    const float* src; int Nn; int base;
    if      (t < 65536)  { src = wv; Nn = 256; base = 0; }
    else if (t < 131072) { src = wo; Nn = 256; base = 65536; }
    else if (t < 163840) { src = wa; Nn = 128; base = 131072; }
    else if (t < 229376) { src = wu; Nn = 256; base = 163840; }
    else                 { src = wf; Nn = 256; base = 229376; }
    const int local = t - base;
    const int n = local >> 8, k = local & 255;
    wt[t] = f2bf(src[k * Nn + n]);
  }
}

// ---- 64x64-tile bf16 MFMA GEMM, full-K LDS via global_load_lds ----
// OUT_MODE: 0 = f32 rows, 1 = bf16 rows, 2 = FP8 head-split vbuf[head][row][32ch x 1B]
template<int NCOL, int OUT_MODE, bool ADD_RES>
__global__ __launch_bounds__(256) void gemm_gl(
    const unsigned short* __restrict__ A, const unsigned short* __restrict__ Bt,
    const float* __restrict__ biasA, const float* __restrict__ biasB,
    const float* __restrict__ RES, void* __restrict__ Cv, int N)
{
  __shared__ unsigned short lds[32768];   // As [0,16384) | Bs [16384,32768)

  const int nwg = 416 * NCOL;             // divisible by 8
  const int lin = blockIdx.x;
  const int swz = (lin & 7) * (nwg >> 3) + (lin >> 3);
  const int brow = (swz / NCOL) * 64;
  const int bcol = (swz % NCOL) * 64;

  const int tid  = threadIdx.x;
  const int wid  = tid >> 6, lane = tid & 63;
  const int wr   = wid >> 1, wc = wid & 1;
  const int fr   = lane & 15, fg = lane >> 4;

  {
    const int r0   = lane >> 3;      // 0..7
    const int slot = lane & 7;       // 16B slot
    #pragma unroll
    for (int t = 0; t < 4; ++t) {
      #pragma unroll
      for (int c = 0; c < 2; ++c) {
        const int row = (wid * 2 + c) * 8 + r0;     // 0..63
        const int gsl = slot ^ (row & 7);
        gl_lds16(A  + (size_t)(brow + row) * 256 + t * 64 + (gsl << 3),
                 &lds[t * 4096 + (wid * 2 + c) * 512]);
        gl_lds16(Bt + (size_t)(bcol + row) * 256 + t * 64 + (gsl << 3),
                 &lds[16384 + t * 4096 + (wid * 2 + c) * 512]);
      }
    }
  }
  __syncthreads();

  f32x4 acc[2][2];
  #pragma unroll
  for (int m = 0; m < 2; ++m)
    #pragma unroll
    for (int n = 0; n < 2; ++n)
      acc[m][n] = (f32x4){0.f, 0.f, 0.f, 0.f};

  #pragma unroll
  for (int t = 0; t < 4; ++t) {
    const char* as = (const char*)&lds[t * 4096];
    const char* bs = (const char*)&lds[16384 + t * 4096];
    #pragma unroll
    for (int kk = 0; kk < 2; ++kk) {
      const int kb = kk * 64 + fg * 16;
      bf16x8 af[2], bfv[2];
      #pragma unroll
      for (int m = 0; m < 2; ++m) {
        const int r = wr * 32 + m * 16 + fr;
        af[m] = *(const bf16x8*)(as + r * 128 + (kb ^ ((r & 7) << 4)));
      }
      #pragma unroll
      for (int n = 0; n < 2; ++n) {
        const int r = wc * 32 + n * 16 + fr;
        bfv[n] = *(const bf16x8*)(bs + r * 128 + (kb ^ ((r & 7) << 4)));
      }
      #pragma unroll
      for (int m = 0; m < 2; ++m)
        #pragma unroll
        for (int n = 0; n < 2; ++n)
          acc[m][n] = __builtin_amdgcn_mfma_f32_16x16x32_bf16(af[m], bfv[n], acc[m][n], 0, 0, 0);
    }
  }

  // ---- epilogue: acc -> LDS (f32 64x64) -> coalesced stores ----
  __syncthreads();
  float* csh = (float*)lds;
  const int c0 = bcol + wc * 32 + fr;
  const int c1 = c0 + 16;
  const float bn0 = (c0 < 256) ? biasA[c0] : biasB[c0 - 256];
  const float bn1 = (c1 < 256) ? biasA[c1] : biasB[c1 - 256];
  #pragma unroll
  for (int m = 0; m < 2; ++m)
    #pragma unroll
    for (int j = 0; j < 4; ++j) {
      const int row = wr * 32 + m * 16 + fg * 4 + j;
      csh[row * 64 + wc * 32 + fr]      = acc[m][0][j] + bn0;
      csh[row * 64 + wc * 32 + 16 + fr] = acc[m][1][j] + bn1;
    }
  __syncthreads();
  #pragma unroll
  for (int i = 0; i < 4; ++i) {
    const int rl = i * 16 + (tid >> 4);
    const int gr = brow + rl;
    if (gr >= M_ROWS) continue;
    const int c4 = (tid & 15) * 4;
    float4 v = *(const float4*)&csh[rl * 64 + c4];
    if (ADD_RES) {
      float4 q = ld4(RES + (size_t)gr * 256 + bcol + c4);
      v.x += q.x; v.y += q.y; v.z += q.z; v.w += q.w;
    }
    if (OUT_MODE == 0) {
      *(float4*)&((float*)Cv)[(size_t)gr * N + bcol + c4] = v;
    } else if (OUT_MODE == 1) {
      ushort4 pk = make_ushort4(f2bf(v.x), f2bf(v.y), f2bf(v.z), f2bf(v.w));
      *(ushort4*)&((unsigned short*)Cv)[(size_t)gr * N + bcol + c4] = pk;
    } else {
      // fp8 e4m3 head-split: vbuf[head][row][32]
      const int head = (bcol + c4) >> 5;
      const int ch   = c4 & 31;
      int r = 0;
      r = __builtin_amdgcn_cvt_pk_fp8_f32(v.x, v.y, r, 0);
      r = __builtin_amdgcn_cvt_pk_fp8_f32(v.z, v.w, r, 1);
      *(int*)&((unsigned char*)Cv)[((size_t)head * M_ROWS + gr) * 32 + ch] = r;
    }
  }
}

// ---- deformable sampling v3: fp8 v, 4 lanes/(q,h), paired x-corners ----
// v: [8][M_ROWS][32] fp8 head-major (x-pair = 64B); oa: [M][384] bf16.
// Block = 64 queries x 1 head x 4 lanes; head = blockIdx&7 (XCD-affine).
// Lane c: x-corner el = c>>1, channel-16-block = c&1; phase1: level = c.
__global__ __launch_bounds__(256) void msda7(
    const unsigned char* __restrict__ v, const unsigned short* __restrict__ oa,
    const float* __restrict__ ref, unsigned short* __restrict__ attout)
{
  constexpr int LW[4] = {100, 50, 25, 13};
  constexpr int LS[4] = {0, 10000, 12500, 13125};

  __shared__ int2   sidx[64][17];   // [q][p] pair-base BYTE offsets (y0,y1); padded
  __shared__ float4 swt [64][17];   // [q][p] weights (y0e0, y0e1, y1e0, y1e1)

  const int bid   = blockIdx.x;
  const int h     = bid & 7;          // head == XCD under %8 round-robin
  const int chunk = bid >> 3;         // 0..415
  const int tid   = threadIdx.x;
  const int q     = tid >> 2;         // query in block 0..63
  const int c     = tid & 3;          // lane-in-group
  const int bq    = chunk * 64 + q;
  const bool active = bq < M_ROWS;
  const int b     = (bq >= NQ) ? 1 : 0;

  if (active) {
    // phase 1: lane owns level l = c (4 points)
    const int l = c;
    const int W = LW[l];
    const float fD = (float)W;
    const unsigned short* oarow = oa + (size_t)bq * 384;

    // softmax over 16 logits, 4 per lane across 4 lanes
    uint2 lg = *(const uint2*)(oarow + 256 + h * 16 + l * 4);
    float g0 = bfu_lo(lg.x), g1 = bfu_hi(lg.x), g2 = bfu_lo(lg.y), g3 = bfu_hi(lg.y);
    float mx = fmaxf(fmaxf(g0, g1), fmaxf(g2, g3));
    mx = fmaxf(mx, __shfl_xor(mx, 1));
    mx = fmaxf(mx, __shfl_xor(mx, 2));
    float e0 = __expf(g0-mx), e1 = __expf(g1-mx), e2 = __expf(g2-mx), e3 = __expf(g3-mx);
    float s = e0 + e1 + e2 + e3;
    s += __shfl_xor(s, 1);
    s += __shfl_xor(s, 2);
    const float inv = 1.f / s;
    const float ee[4] = {e0*inv, e1*inv, e2*inv, e3*inv};

    uint4 ov = *(const uint4*)(oarow + h * 32 + l * 8);
    const float oxy[8] = {bfu_lo(ov.x), bfu_hi(ov.x), bfu_lo(ov.y), bfu_hi(ov.y),
                          bfu_lo(ov.z), bfu_hi(ov.z), bfu_lo(ov.w), bfu_hi(ov.w)};
    const float rx = ref[(size_t)bq * 8 + l * 2];
    const float ry = ref[(size_t)bq * 8 + l * 2 + 1];
    const int rowbase = b * NV + LS[l];

    #pragma unroll
    for (int j = 0; j < 4; ++j) {
      const float x = fmaf(rx, fD, oxy[2*j])   - 0.5f;
      const float y = fmaf(ry, fD, oxy[2*j+1]) - 0.5f;
      const float x0f = floorf(x), y0f = floorf(y);
      const float lx = x - x0f, ly = y - y0f;
      const int x0 = (int)x0f, y0 = (int)y0f;
      const int y1 = y0 + 1;
      const int xbase = min(max(x0, 0), W - 2);
      const float wx0 = 1.f - lx, wx1 = lx;
      const float we0 = (x0 == xbase     ? wx0 : 0.f) + (x0 == xbase - 1 ? wx1 : 0.f);
      const float we1 = (x0 == xbase + 1 ? wx0 : 0.f) + (x0 == xbase     ? wx1 : 0.f);
      const int cy0 = min(max(y0, 0), W - 1), cy1 = min(max(y1, 0), W - 1);
      const float wy0 = (y0 >= 0 && y0 < W) ? (1.f - ly) : 0.f;
      const float wy1 = (y1 >= 0 && y1 < W) ? ly : 0.f;
      const float wt = ee[j];
      const int p = l * 4 + j;
      sidx[q][p] = make_int2((rowbase + cy0 * W + xbase) * 32,
                             (rowbase + cy1 * W + xbase) * 32);
      swt[q][p] = make_float4(wt * wy0 * we0, wt * wy0 * we1,
                              wt * wy1 * we0, wt * wy1 * we1);
    }
  }
  __syncthreads();

  if (active) {
    const unsigned char* vb = v + (size_t)h * M_ROWS * 32 + c * 16;
    const int el = c >> 1;   // x-corner element this lane holds
    f32x2 acc2[8];           // 16 channels
    #pragma unroll
    for (int k = 0; k < 8; ++k) acc2[k] = (f32x2){0.f, 0.f};
    #pragma unroll
    for (int p = 0; p < 16; ++p) {
      const int2   ix = sidx[q][p];
      const float4 w4 = swt[q][p];
      uint4 r0 = *(const uint4*)(vb + ix.x);   // y0 pair, my 16 fp8
      uint4 r1 = *(const uint4*)(vb + ix.y);   // y1 pair, my 16 fp8
      const float wa = el ? w4.y : w4.x;
      const float wb = el ? w4.w : w4.z;
      const f32x2 wav = (f32x2){wa, wa};
      const f32x2 wbv = (f32x2){wb, wb};
      acc2[0] = wav * __builtin_amdgcn_cvt_pk_f32_fp8(r0.x, 0) + acc2[0];
      acc2[1] = wav * __builtin_amdgcn_cvt_pk_f32_fp8(r0.x, 1) + acc2[1];
      acc2[2] = wav * __builtin_amdgcn_cvt_pk_f32_fp8(r0.y, 0) + acc2[2];
      acc2[3] = wav * __builtin_amdgcn_cvt_pk_f32_fp8(r0.y, 1) + acc2[3];
      acc2[4] = wav * __builtin_amdgcn_cvt_pk_f32_fp8(r0.z, 0) + acc2[4];
      acc2[5] = wav * __builtin_amdgcn_cvt_pk_f32_fp8(r0.z, 1) + acc2[5];
      acc2[6] = wav * __builtin_amdgcn_cvt_pk_f32_fp8(r0.w, 0) + acc2[6];
      acc2[7] = wav * __builtin_amdgcn_cvt_pk_f32_fp8(r0.w, 1) + acc2[7];
      acc2[0] = wbv * __builtin_amdgcn_cvt_pk_f32_fp8(r1.x, 0) + acc2[0];
      acc2[1] = wbv * __builtin_amdgcn_cvt_pk_f32_fp8(r1.x, 1) + acc2[1];
      acc2[2] = wbv * __builtin_amdgcn_cvt_pk_f32_fp8(r1.y, 0) + acc2[2];
      acc2[3] = wbv * __builtin_amdgcn_cvt_pk_f32_fp8(r1.y, 1) + acc2[3];
      acc2[4] = wbv * __builtin_amdgcn_cvt_pk_f32_fp8(r1.z, 0) + acc2[4];
      acc2[5] = wbv * __builtin_amdgcn_cvt_pk_f32_fp8(r1.z, 1) + acc2[5];
      acc2[6] = wbv * __builtin_amdgcn_cvt_pk_f32_fp8(r1.w, 0) + acc2[6];
      acc2[7] = wbv * __builtin_amdgcn_cvt_pk_f32_fp8(r1.w, 1) + acc2[7];
    }
    // merge x-corner halves: lane c ^ 2 holds same channels, other corner
    #pragma unroll
    for (int k = 0; k < 8; ++k) {
      acc2[k][0] += __shfl_xor(acc2[k][0], 2);
      acc2[k][1] += __shfl_xor(acc2[k][1], 2);
    }
    if (c < 2) {   // c=0: ch0-15, c=1: ch16-31
      uint4 pkA, pkB;
      pkA.x = pk2(acc2[0][0], acc2[0][1]);
      pkA.y = pk2(acc2[1][0], acc2[1][1]);
      pkA.z = pk2(acc2[2][0], acc2[2][1]);
      pkA.w = pk2(acc2[3][0], acc2[3][1]);
      pkB.x = pk2(acc2[4][0], acc2[4][1]);
      pkB.y = pk2(acc2[5][0], acc2[5][1]);
      pkB.z = pk2(acc2[6][0], acc2[6][1]);
      pkB.w = pk2(acc2[7][0], acc2[7][1]);
      unsigned short* dst = attout + (size_t)bq * 256 + h * 32 + c * 16;
      *(uint4*)dst = pkA;
      *(uint4*)(dst + 8) = pkB;
    }
  }
}

extern "C" void kernel_launch(void* const* d_in, const int* in_sizes, int n_in,
                              void* d_out, int out_size, void* d_ws, size_t ws_size,
                              hipStream_t stream) {
  const float* query  = (const float*)d_in[0];
  const float* value  = (const float*)d_in[2];
  const float* qpos   = (const float*)d_in[3];
  const float* refpts = (const float*)d_in[4];
  const float* W_value = (const float*)d_in[8];
  const float* b_value = (const float*)d_in[9];
  const float* W_off   = (const float*)d_in[10];
  const float* b_off   = (const float*)d_in[11];
  const float* W_attn  = (const float*)d_in[12];
  const float* b_attn  = (const float*)d_in[13];
  const float* W_out   = (const float*)d_in[14];
  const float* b_out   = (const float*)d_in[15];
  const float* W_ffn   = (const float*)d_in[16];
  const float* b_ffn   = (const float*)d_in[17];
  float* out = (float*)d_out;

  // workspace layout (~55 MB)
  unsigned short* oa    = (unsigned short*)d_ws;          // (MP,384) bf16
  unsigned char*  vbuf8 = (unsigned char*)(oa + (size_t)MP * 384);  // [8][M][32] fp8
  unsigned short* AB1   = (unsigned short*)(vbuf8 + (size_t)8 * M_ROWS * 32); // val_bf -> attout
  unsigned short* AB2   = AB1 + (size_t)MP * 256;         // q_bf -> tmp bf16
  unsigned short* wts   = AB2 + (size_t)MP * 256;
  unsigned short* wv_t  = wts;
  unsigned short* woa_t = wts + 65536;   // [W_off^T ; W_attn^T]
  unsigned short* wu_t  = wts + 163840;
  unsigned short* wf_t  = wts + 229376;

  const dim3 blk(256);

  prep_all<<<dim3(2048), blk, 0, stream>>>(value, query, qpos, AB1, AB2,
      W_value, W_off, W_attn, W_out, W_ffn, wts);

  // v = value @ W_value + b -> vbuf8 head-split fp8
  gemm_gl<4,2,false><<<dim3(1664), blk, 0, stream>>>(
      AB1, wv_t, b_value, b_value, nullptr, vbuf8, 256);
  // [off | attn] = (q+pos) @ [W_off;W_attn] + biases -> bf16 (M,384)
  gemm_gl<6,1,false><<<dim3(2496), blk, 0, stream>>>(
      AB2, woa_t, b_off, b_attn, nullptr, oa, 384);
  // deformable sampling -> attout bf16 (overwrites AB1)
  msda7<<<dim3(8 * 416), blk, 0, stream>>>(vbuf8, oa, refpts, AB1);
  // tmp = attout @ W_out + b_out + query -> bf16 (overwrites AB2)
  gemm_gl<4,1,true><<<dim3(1664), blk, 0, stream>>>(
      AB1, wu_t, b_out, b_out, query, AB2, 256);
  // out = tmp @ W_ffn + b_ffn -> f32
  gemm_gl<4,0,false><<<dim3(1664), blk, 0, stream>>>(
      AB2, wf_t, b_ffn, b_ffn, nullptr, (void*)out, 256);
}